// Round 23
// baseline (66.771 us; speedup 1.0000x reference)
//
#include <hip/hip_runtime.h>
#include <hip/hip_fp16.h>

#define KSZ 11
#define RMOD 48       /* ring rows; slot = q % 48 */
#define GH 13         /* ghost rows: V reads slots sb..sb+13, sb <= 47 */
#define ROWB 512      /* bytes per LDS row (union: lin <=31 units, hbuf 32) */
#define THREADS 256
#define NCHUNK 4      /* 4 chunks x 32 rows = 128-row segment */

// Normalized 1-D Gaussian, sigma=1.5, K=11.
#define W0 1.0283800e-03f
#define W1 7.5987000e-03f
#define W2 3.6000800e-02f
#define W3 1.0936070e-01f
#define W4 2.1300550e-01f
#define W5 2.6601170e-01f

struct Pix8   { __half2 hx, hy; };                 // staged input px (2ch x,y)
struct Pix8x2 { __half2 hx0, hy0, hx1, hy1; };     // two adjacent Pix8 (16B)
struct Pix16  { __half2 s0, s1, s2, s3; };         // H-blurred 4 signals (16B)

// hbuf column swizzle (R16-proven): logical col 4g+j -> ((g+2j)&7)|(j<<3).
#define HBCOL(g, j) ((((g) + 2 * (j)) & 7) | ((j) << 3))

static __device__ __forceinline__ __half2 pkrtz(float a, float b) {
    auto v = __builtin_amdgcn_cvt_pkrtz(a, b);
    __half2 r;
    __builtin_memcpy(&r, &v, 4);
    return r;
}

// T14 async-STAGE split, retried on the 5-block/CU config (R18 tested it on
// 4-block/CU where the occupancy loss masked the gain): load chunk rows into
// 24 regs early, write them to LDS after the next barrier.
static __device__ __forceinline__ void stage_load(
    const float* __restrict__ x, const float* __restrict__ y,
    size_t base0, size_t base1, int q, int g, int tileC, bool colInt,
    float2 rx0[3], float2 rx1[3], float2 ry0[3], float2 ry1[3])
{
    const int c0 = 6 * g;
    if (colInt && q < 512) {               // main-loop q >= 5 always
        const size_t goff = (size_t)q * 512 + (size_t)(tileC - 8 + c0);
        const float2* X0 = (const float2*)(x + base0 + goff);
        const float2* X1 = (const float2*)(x + base1 + goff);
        const float2* Y0 = (const float2*)(y + base0 + goff);
        const float2* Y1 = (const float2*)(y + base1 + goff);
#pragma unroll
        for (int m = 0; m < 3; ++m) {
            rx0[m] = X0[m]; rx1[m] = X1[m];
            ry0[m] = Y0[m]; ry1[m] = Y1[m];
        }
    } else {
#pragma unroll
        for (int m = 0; m < 3; ++m) {
            float2 a0 = {0.f, 0.f}, a1 = {0.f, 0.f};
            float2 b0 = {0.f, 0.f}, b1 = {0.f, 0.f};
#pragma unroll
            for (int e = 0; e < 2; ++e) {
                const int gc = tileC - 8 + c0 + 2 * m + e;
                if (q >= 0 && q < 512 && gc >= 0 && gc < 512) {
                    const size_t gg = (size_t)q * 512 + (size_t)gc;
                    if (e == 0) { a0.x = x[base0+gg]; a1.x = x[base1+gg];
                                  b0.x = y[base0+gg]; b1.x = y[base1+gg]; }
                    else        { a0.y = x[base0+gg]; a1.y = x[base1+gg];
                                  b0.y = y[base0+gg]; b1.y = y[base1+gg]; }
                }
            }
            rx0[m] = a0; rx1[m] = a1; ry0[m] = b0; ry1[m] = b1;
        }
    }
}

// Pack + write to rotated lin ring slot (rot kills the H-read 2-way conflict).
static __device__ __forceinline__ void stage_write(
    int g, int s, int rot, Pix8* lin,
    const float2 rx0[3], const float2 rx1[3],
    const float2 ry0[3], const float2 ry1[3])
{
    const int c0 = 6 * g;
    Pix8x2* dst = (Pix8x2*)&lin[s * 64 + c0 + rot];  // rot even -> 16B aligned
#pragma unroll
    for (int m = 0; m < 3; ++m) {
        Pix8x2 o;
        o.hx0 = pkrtz(rx0[m].x, rx1[m].x);
        o.hy0 = pkrtz(ry0[m].x, ry1[m].x);
        o.hx1 = pkrtz(rx0[m].y, rx1[m].y);
        o.hy1 = pkrtz(ry0[m].y, ry1[m].y);
        dst[m] = o;
    }
}

// H-blur ring slot s (reads rotated lin row s, writes hbuf row s + ghost dup).
static __device__ __forceinline__ void h_item(
    int g, int s, int rot, Pix8* lin, Pix16* hb, const __half2* w2, __half2 hz)
{
    const int c0 = g << 2;
    __half2 wx[16], wy[16];
    const Pix8x2* src = (const Pix8x2*)&lin[s * 64 + (c0 + 2) + rot];
#pragma unroll
    for (int k = 0; k < 8; ++k) {
        Pix8x2 u = src[k];
        wx[2*k]   = u.hx0; wy[2*k]   = u.hy0;
        wx[2*k+1] = u.hx1; wy[2*k+1] = u.hy1;
    }
    __half2 pp[16], qq[16];
#pragma unroll
    for (int k = 1; k < 15; ++k) {
        pp[k] = __hfma2(wy[k], wy[k], __hmul2(wx[k], wx[k]));  // x^2+y^2
        qq[k] = __hmul2(wx[k], wy[k]);                          // x*y
    }
    __half2 s0[4] = {hz, hz, hz, hz}, s1[4] = {hz, hz, hz, hz};
    __half2 s2[4] = {hz, hz, hz, hz}, s3[4] = {hz, hz, hz, hz};
#pragma unroll
    for (int k = 1; k < 15; ++k) {
#pragma unroll
        for (int j = 0; j < 4; ++j) {
            const int tt = k - 1 - j;
            if (tt >= 0 && tt < KSZ) {
                s0[j] = __hfma2(w2[tt], wx[k], s0[j]);
                s1[j] = __hfma2(w2[tt], wy[k], s1[j]);
                s2[j] = __hfma2(w2[tt], pp[k], s2[j]);
                s3[j] = __hfma2(w2[tt], qq[k], s3[j]);
            }
        }
    }
    Pix16* orow = &hb[s * 32];
#pragma unroll
    for (int j = 0; j < 4; ++j) {
        Pix16 v;
        v.s0 = s0[j]; v.s1 = s1[j]; v.s2 = s2[j]; v.s3 = s3[j];
        orow[HBCOL(g, j)] = v;
    }
    if (s < GH) {                       // ghost dup so V reads never wrap
        Pix16* orow2 = orow + RMOD * 32;
#pragma unroll
        for (int j = 0; j < 4; ++j) {
            Pix16 v;
            v.s0 = s0[j]; v.s1 = s1[j]; v.s2 = s2[j]; v.s3 = s3[j];
            orow2[HBCOL(g, j)] = v;
        }
    }
}

// Rolling-strip SSIM (R19/R22 structure, 5 blocks/CU) + register prefetch:
// chunk n+1's global loads issue right after chunk n's regs are consumed,
// riding under H(n)+V(n) (~2000cyc) instead of stalling stage(n+1).
__global__ __launch_bounds__(THREADS) void ssim_roll_kernel(
    const float* __restrict__ x, const float* __restrict__ y,
    float* __restrict__ partial)
{
    __shared__ __align__(16) unsigned char smem[(RMOD + GH) * ROWB]; // 31232 B
    __shared__ float wsum[THREADS / 64];
    Pix8*  lin = (Pix8*)smem;
    Pix16* hb  = (Pix16*)smem;

    const __half2 w2[KSZ] = {
        __float2half2_rn(W0), __float2half2_rn(W1), __float2half2_rn(W2),
        __float2half2_rn(W3), __float2half2_rn(W4), __float2half2_rn(W5),
        __float2half2_rn(W4), __float2half2_rn(W3), __float2half2_rn(W2),
        __float2half2_rn(W1), __float2half2_rn(W0)};
    const __half2 hz = __float2half2_rn(0.0f);

    const int tid = threadIdx.x;
    const int bx = blockIdx.x;                     // 0..63
    // XCD swizzle: XCD k (= bx&7) owns strips 2k,2k+1 (all 4 segments)
    const int t  = ((bx & 7) << 3) | (bx >> 3);    // bijective 0..63
    const int sx = t >> 2;                         // column strip 0..15
    const int sg = t & 3;                          // row segment 0..3
    const int B  = sg << 7;                        // first output row
    const int tileC = sx << 5;
    const bool colInt = (sx > 0) && (sx < 15);
    const size_t plane = 512 * 512;
    const size_t base0 = (size_t)blockIdx.y * 2 * plane;   // channel 0
    const size_t base1 = base0 + plane;                    // channel 1

    const int st_ro = tid >> 3, st_g = tid & 7;

    // Preload chunk 0 FIRST so its latency hides under the prologue work.
    float2 rx0[3], rx1[3], ry0[3], ry1[3];
    stage_load(x, y, base0, base1, B + 5 + st_ro, st_g, tileC, colInt,
               rx0, rx1, ry0, ry1);

    // ---- Prologue: hbuf rows B-5..B+4 (10 rows, 80 items) ----
    {
        const int pro_q = B - 5 + (tid >> 3);
        const int pro_g = tid & 7;
        const int pro_s = (pro_q + 480) % RMOD;    // +480 keeps operand >= 0
        const int pro_rot = (pro_s & 7) << 1;
        if (tid < 80) {
            if (pro_q >= 0) {
                float2 px0[3], px1[3], py0[3], py1[3];
                stage_load(x, y, base0, base1, pro_q, pro_g, tileC, colInt,
                           px0, px1, py0, py1);
                stage_write(pro_g, pro_s, pro_rot, lin, px0, px1, py0, py1);
                h_item(pro_g, pro_s, pro_rot, lin, hb, w2, hz);
            } else {       // rows < 0: blur of zero padding = zeros
                Pix16 z; z.s0 = hz; z.s1 = hz; z.s2 = hz; z.s3 = hz;
                Pix16* orow = &hb[pro_s * 32];     // pro_s in [43,47]: no ghost
#pragma unroll
                for (int j = 0; j < 4; ++j) orow[HBCOL(pro_g, j)] = z;
            }
        }
    }

    // ---- 4 chunks of 32 rows, register-pipelined staging ----
    float bsum = 0.f;
    const int v_c = tid & 31, v_rg = tid >> 5;
    const int pc = HBCOL(v_c >> 2, v_c & 3);
    const __half2 c1h  = __float2half2_rn(1.0e-4f);
    const __half2 c2h  = __float2half2_rn(9.0e-4f);
    const __half2 twoh = __float2half2_rn(2.0f);

#pragma unroll 1
    for (int n = 0; n < NCHUNK; ++n) {
        __syncthreads();   // V(n-1) ring reads done before slots reused
        const int q = B + (n << 5) + 5 + st_ro;    // input rows [B+32n+5, +36]
        const int s = q % RMOD;
        const int rot = (s & 7) << 1;
        stage_write(st_g, s, rot, lin, rx0, rx1, ry0, ry1);
        if (n < NCHUNK - 1)                        // prefetch chunk n+1 now;
            stage_load(x, y, base0, base1, q + 32, st_g, tileC, colInt,
                       rx0, rx1, ry0, ry1);        // latency hides under H+V
        h_item(st_g, s, rot, lin, hb, w2, hz);     // octet-local: no barrier
        __syncthreads();   // all 42 hbuf rows of this window ready

        // V-pass: output rows B+32n+4*v_rg .. +3, col v_c
        const int sb = (B + (n << 5) + (v_rg << 2) - 5 + 480) % RMOD;
        const Pix16* colp = &hb[sb * 32 + pc];     // reads sb..sb+13 (ghosts)

        __half2 b0[4] = {hz, hz, hz, hz}, b1[4] = {hz, hz, hz, hz};
        __half2 b2[4] = {hz, hz, hz, hz}, b3[4] = {hz, hz, hz, hz};
#pragma unroll
        for (int k = 0; k < 14; ++k) {
            Pix16 u = colp[k * 32];                // byte offset k*512: static
#pragma unroll
            for (int j = 0; j < 4; ++j) {
                const int tt = k - j;
                if (tt >= 0 && tt < KSZ) {
                    b0[j] = __hfma2(w2[tt], u.s0, b0[j]);
                    b1[j] = __hfma2(w2[tt], u.s1, b1[j]);
                    b2[j] = __hfma2(w2[tt], u.s2, b2[j]);
                    b3[j] = __hfma2(w2[tt], u.s3, b3[j]);
                }
            }
        }
        __half2 acc2 = hz;
#pragma unroll
        for (int j = 0; j < 4; ++j) {
            __half2 ux = b0[j], uy = b1[j], up = b2[j], uq = b3[j];
            __half2 uxuy  = __hmul2(ux, uy);
            __half2 sumsq = __hfma2(ux, ux, __hmul2(uy, uy));
            __half2 vsum  = __hsub2(up, sumsq);            // vx + vy
            __half2 vxy   = __hsub2(uq, uxuy);
            __half2 num   = __hmul2(__hfma2(twoh, uxuy, c1h),
                                    __hfma2(twoh, vxy, c2h));
            __half2 den   = __hmul2(__hadd2(sumsq, c1h), __hadd2(vsum, c2h));
            acc2 = __hfma2(num, h2rcp(den), acc2);
        }
        float2 af = __half22float2(acc2);
        bsum += af.x + af.y;
    }

    // ---- Wave shuffle reduce, cross-wave via LDS ----
#pragma unroll
    for (int off = 32; off > 0; off >>= 1) bsum += __shfl_down(bsum, off, 64);
    const int lane = tid & 63, wid = tid >> 6;
    if (lane == 0) wsum[wid] = bsum;
    __syncthreads();
    if (tid == 0) {
        float tot = 0.f;
#pragma unroll
        for (int i = 0; i < THREADS / 64; ++i) tot += wsum[i];
        partial[(size_t)blockIdx.y * gridDim.x + blockIdx.x] = tot;
    }
}

// Final deterministic reduction: n partials (float4-vectorized) ->
// out[0] = 1 - sum/count.
__global__ __launch_bounds__(256) void ssim_reduce_kernel(
    const float* __restrict__ partial, int n, float* __restrict__ out,
    double inv_count)
{
    __shared__ double ws[4];
    const float4* p4 = (const float4*)partial;
    const int n4 = n >> 2;
    double s = 0.0;
    for (int i = threadIdx.x; i < n4; i += 256) {
        float4 v = p4[i];
        s += (double)v.x + (double)v.y + (double)v.z + (double)v.w;
    }
#pragma unroll
    for (int off = 32; off > 0; off >>= 1) s += __shfl_down(s, off, 64);
    int lane = threadIdx.x & 63, wid = threadIdx.x >> 6;
    if (lane == 0) ws[wid] = s;
    __syncthreads();
    if (threadIdx.x == 0) {
        double tot = ws[0] + ws[1] + ws[2] + ws[3];
        out[0] = (float)(1.0 - tot * inv_count);
    }
}

extern "C" void kernel_launch(void* const* d_in, const int* in_sizes, int n_in,
                              void* d_out, int out_size, void* d_ws, size_t ws_size,
                              hipStream_t stream) {
    const float* x = (const float*)d_in[0];
    const float* y = (const float*)d_in[1];
    float* partial = (float*)d_ws;

    const int N = 32;
    dim3 grid(64, N);   // 16 strips x 4 segments; grid.y = batch (C packed)
    ssim_roll_kernel<<<grid, THREADS, 0, stream>>>(x, y, partial);

    const int nPartial = 64 * N;                       // 2048
    const double inv_count = 1.0 / ((double)N * 2 * 512 * 512);
    ssim_reduce_kernel<<<1, 256, 0, stream>>>(partial, nPartial, (float*)d_out,
                                              inv_count);
}

// Round 24
// 65.996 us; speedup vs baseline: 1.0117x; 1.0117x over previous
//
#include <hip/hip_runtime.h>
#include <hip/hip_fp16.h>

#define KSZ 11
#define RMOD 74       /* ring rows = exact live window; write-vs-live-read
                         row distance is [1,73], never 0 mod 74 -> barrier A
                         (V(n-1) vs stage(n)) is provably redundant */
#define ROWB 512      /* bytes per LDS row (union: lin <=62 Pix8, hbuf 32) */
#define THREADS 256
#define NCHUNK 4      /* 4 chunks x 32 rows = 128-row segment */

// Normalized 1-D Gaussian, sigma=1.5, K=11.
#define W0 1.0283800e-03f
#define W1 7.5987000e-03f
#define W2 3.6000800e-02f
#define W3 1.0936070e-01f
#define W4 2.1300550e-01f
#define W5 2.6601170e-01f

struct Pix8   { __half2 hx, hy; };                 // staged input px (2ch x,y)
struct Pix8x2 { __half2 hx0, hy0, hx1, hy1; };     // two adjacent Pix8 (16B)
struct Pix16  { __half2 s0, s1, s2, s3; };         // H-blurred 4 signals (16B)

// hbuf column swizzle (R16-proven): logical col 4g+j -> ((g+2j)&7)|(j<<3).
#define HBCOL(g, j) ((((g) + 2 * (j)) & 7) | ((j) << 3))

static __device__ __forceinline__ __half2 pkrtz(float a, float b) {
    auto v = __builtin_amdgcn_cvt_pkrtz(a, b);
    __half2 r;
    __builtin_memcpy(&r, &v, 4);
    return r;
}

// Stage global row q (48-col strip, base tileC-8) into rotated lin slot s.
// rot=(s&7)*2 Pix8 units: keeps H-read bank quads uniform (R22, conflicts /3).
static __device__ __forceinline__ void stage_item(
    const float* __restrict__ x, const float* __restrict__ y,
    size_t base0, size_t base1, int q, int g, int s, int rot, int tileC,
    bool fast, Pix8* lin)
{
    const int c0 = 6 * g;
    Pix8 p[6];
    if (fast) {  // col-interior strip AND q < 512 (q >= 0 guaranteed here)
        const size_t goff = (size_t)q * 512 + (size_t)(tileC - 8 + c0);
        const float2* X0 = (const float2*)(x + base0 + goff);
        const float2* X1 = (const float2*)(x + base1 + goff);
        const float2* Y0 = (const float2*)(y + base0 + goff);
        const float2* Y1 = (const float2*)(y + base1 + goff);
#pragma unroll
        for (int m = 0; m < 3; ++m) {
            float2 a0 = X0[m], a1 = X1[m], b0 = Y0[m], b1 = Y1[m];
            p[2*m].hx   = pkrtz(a0.x, a1.x);
            p[2*m].hy   = pkrtz(b0.x, b1.x);
            p[2*m+1].hx = pkrtz(a0.y, a1.y);
            p[2*m+1].hy = pkrtz(b0.y, b1.y);
        }
    } else {
#pragma unroll
        for (int m = 0; m < 6; ++m) {
            const int gc = tileC - 8 + c0 + m;
            float x0 = 0.f, x1 = 0.f, y0 = 0.f, y1 = 0.f;
            if (q >= 0 && q < 512 && gc >= 0 && gc < 512) {
                const size_t gg = (size_t)q * 512 + (size_t)gc;
                x0 = x[base0 + gg]; x1 = x[base1 + gg];
                y0 = y[base0 + gg]; y1 = y[base1 + gg];
            }
            p[m].hx = pkrtz(x0, x1);
            p[m].hy = pkrtz(y0, y1);
        }
    }
    Pix8x2* dst = (Pix8x2*)&lin[s * 64 + c0 + rot];  // rot even -> 16B aligned
#pragma unroll
    for (int m = 0; m < 3; ++m) {
        Pix8x2 o;
        o.hx0 = p[2*m].hx;   o.hy0 = p[2*m].hy;
        o.hx1 = p[2*m+1].hx; o.hy1 = p[2*m+1].hy;
        dst[m] = o;
    }
}

// H-blur ring slot s (reads rotated lin row s, writes hbuf row s; no ghosts).
static __device__ __forceinline__ void h_item(
    int g, int s, int rot, Pix8* lin, Pix16* hb, const __half2* w2, __half2 hz)
{
    const int c0 = g << 2;
    __half2 wx[16], wy[16];
    const Pix8x2* src = (const Pix8x2*)&lin[s * 64 + (c0 + 2) + rot];
#pragma unroll
    for (int k = 0; k < 8; ++k) {
        Pix8x2 u = src[k];
        wx[2*k]   = u.hx0; wy[2*k]   = u.hy0;
        wx[2*k+1] = u.hx1; wy[2*k+1] = u.hy1;
    }
    __half2 pp[16], qq[16];
#pragma unroll
    for (int k = 1; k < 15; ++k) {
        pp[k] = __hfma2(wy[k], wy[k], __hmul2(wx[k], wx[k]));  // x^2+y^2
        qq[k] = __hmul2(wx[k], wy[k]);                          // x*y
    }
    __half2 s0[4] = {hz, hz, hz, hz}, s1[4] = {hz, hz, hz, hz};
    __half2 s2[4] = {hz, hz, hz, hz}, s3[4] = {hz, hz, hz, hz};
#pragma unroll
    for (int k = 1; k < 15; ++k) {
#pragma unroll
        for (int j = 0; j < 4; ++j) {
            const int tt = k - 1 - j;
            if (tt >= 0 && tt < KSZ) {
                s0[j] = __hfma2(w2[tt], wx[k], s0[j]);
                s1[j] = __hfma2(w2[tt], wy[k], s1[j]);
                s2[j] = __hfma2(w2[tt], pp[k], s2[j]);
                s3[j] = __hfma2(w2[tt], qq[k], s3[j]);
            }
        }
    }
    Pix16* orow = &hb[s * 32];
#pragma unroll
    for (int j = 0; j < 4; ++j) {
        Pix16 v;
        v.s0 = s0[j]; v.s1 = s1[j]; v.s2 = s2[j]; v.s3 = s3[j];
        orow[HBCOL(g, j)] = v;
    }
}

// Rolling-strip SSIM, ONE barrier per chunk: [stage -> H -> barrier -> V].
// The 74-slot ring makes stage(n)/H(n) writes collision-free with V(n-1)
// reads (distance [1,73] mod 74 != 0), so the old barrier A is removed;
// waves finishing V early immediately issue the next chunk's global loads,
// overlapping load latency with other waves' V tail for free.
__global__ __launch_bounds__(THREADS) void ssim_roll_kernel(
    const float* __restrict__ x, const float* __restrict__ y,
    float* __restrict__ partial)
{
    __shared__ __align__(16) unsigned char smem[RMOD * ROWB];  // 37888 B
    __shared__ float wsum[THREADS / 64];
    Pix8*  lin = (Pix8*)smem;
    Pix16* hb  = (Pix16*)smem;

    const __half2 w2[KSZ] = {
        __float2half2_rn(W0), __float2half2_rn(W1), __float2half2_rn(W2),
        __float2half2_rn(W3), __float2half2_rn(W4), __float2half2_rn(W5),
        __float2half2_rn(W4), __float2half2_rn(W3), __float2half2_rn(W2),
        __float2half2_rn(W1), __float2half2_rn(W0)};
    const __half2 hz = __float2half2_rn(0.0f);

    const int tid = threadIdx.x;
    const int bx = blockIdx.x;                     // 0..63
    // XCD swizzle: XCD k (= bx&7) owns strips 2k,2k+1 (all 4 segments)
    const int t  = ((bx & 7) << 3) | (bx >> 3);    // bijective 0..63
    const int sx = t >> 2;                         // column strip 0..15
    const int sg = t & 3;                          // row segment 0..3
    const int B  = sg << 7;                        // first output row
    const int tileC = sx << 5;
    const bool colInt = (sx > 0) && (sx < 15);
    const size_t plane = 512 * 512;
    const size_t base0 = (size_t)blockIdx.y * 2 * plane;   // channel 0
    const size_t base1 = base0 + plane;                    // channel 1

    // ---- Prologue: hbuf rows B-5..B+4 (10 rows, 80 items) ----
    {
        const int pro_q = B - 5 + (tid >> 3);
        const int pro_g = tid & 7;
        const int pro_s = (pro_q + 740) % RMOD;    // +740 = 10*74 keeps >= 0
        const int pro_rot = (pro_s & 7) << 1;
        if (tid < 80) {
            if (pro_q >= 0) {
                stage_item(x, y, base0, base1, pro_q, pro_g, pro_s, pro_rot,
                           tileC, colInt, lin);
                h_item(pro_g, pro_s, pro_rot, lin, hb, w2, hz);
            } else {       // rows < 0: blur of zero padding = zeros
                Pix16 z; z.s0 = hz; z.s1 = hz; z.s2 = hz; z.s3 = hz;
                Pix16* orow = &hb[pro_s * 32];     // pro_s in [69,73]
#pragma unroll
                for (int j = 0; j < 4; ++j) orow[HBCOL(pro_g, j)] = z;
            }
        }
    }

    // ---- 4 chunks of 32 rows, ONE barrier each ----
    float bsum = 0.f;
    const int st_ro = tid >> 3, st_g = tid & 7;
    const int v_c = tid & 31, v_rg = tid >> 5;
    const int pc = HBCOL(v_c >> 2, v_c & 3);
    const __half2 c1h  = __float2half2_rn(1.0e-4f);
    const __half2 c2h  = __float2half2_rn(9.0e-4f);
    const __half2 twoh = __float2half2_rn(2.0f);

#pragma unroll 1
    for (int n = 0; n < NCHUNK; ++n) {
        // stage(n)+H(n): slots at row-distance [1,73] from V(n-1) reads ->
        // disjoint mod 74 -> safe without a barrier (cross-wave too).
        const int q = B + (n << 5) + 5 + st_ro;    // input rows [B+32n+5, +36]
        const int s = q % RMOD;
        const int rot = (s & 7) << 1;
        const bool fast = colInt && (q < 512);
        stage_item(x, y, base0, base1, q, st_g, s, rot, tileC, fast, lin);
        h_item(st_g, s, rot, lin, hb, w2, hz);     // octet-local: no barrier
        __syncthreads();   // all 42 hbuf rows of this window ready

        // V-pass: output rows B+32n+4*v_rg .. +3, col v_c.
        // Wrap-select: slots sb..sb+13 mod 74 (wraps at most once).
        const int sb = (B + (n << 5) + (v_rg << 2) - 5 + 740) % RMOD;

        __half2 b0[4] = {hz, hz, hz, hz}, b1[4] = {hz, hz, hz, hz};
        __half2 b2[4] = {hz, hz, hz, hz}, b3[4] = {hz, hz, hz, hz};
#pragma unroll
        for (int k = 0; k < 14; ++k) {
            int sk = sb + k;
            sk -= (sk >= RMOD) ? RMOD : 0;
            Pix16 u = hb[sk * 32 + pc];
#pragma unroll
            for (int j = 0; j < 4; ++j) {
                const int tt = k - j;
                if (tt >= 0 && tt < KSZ) {
                    b0[j] = __hfma2(w2[tt], u.s0, b0[j]);
                    b1[j] = __hfma2(w2[tt], u.s1, b1[j]);
                    b2[j] = __hfma2(w2[tt], u.s2, b2[j]);
                    b3[j] = __hfma2(w2[tt], u.s3, b3[j]);
                }
            }
        }
        __half2 acc2 = hz;
#pragma unroll
        for (int j = 0; j < 4; ++j) {
            __half2 ux = b0[j], uy = b1[j], up = b2[j], uq = b3[j];
            __half2 uxuy  = __hmul2(ux, uy);
            __half2 sumsq = __hfma2(ux, ux, __hmul2(uy, uy));
            __half2 vsum  = __hsub2(up, sumsq);            // vx + vy
            __half2 vxy   = __hsub2(uq, uxuy);
            __half2 num   = __hmul2(__hfma2(twoh, uxuy, c1h),
                                    __hfma2(twoh, vxy, c2h));
            __half2 den   = __hmul2(__hadd2(sumsq, c1h), __hadd2(vsum, c2h));
            acc2 = __hfma2(num, h2rcp(den), acc2);
        }
        float2 af = __half22float2(acc2);
        bsum += af.x + af.y;
    }

    // ---- Wave shuffle reduce, cross-wave via LDS ----
#pragma unroll
    for (int off = 32; off > 0; off >>= 1) bsum += __shfl_down(bsum, off, 64);
    const int lane = tid & 63, wid = tid >> 6;
    if (lane == 0) wsum[wid] = bsum;
    __syncthreads();
    if (tid == 0) {
        float tot = 0.f;
#pragma unroll
        for (int i = 0; i < THREADS / 64; ++i) tot += wsum[i];
        partial[(size_t)blockIdx.y * gridDim.x + blockIdx.x] = tot;
    }
}

// Final deterministic reduction: n partials (float4-vectorized) ->
// out[0] = 1 - sum/count.
__global__ __launch_bounds__(256) void ssim_reduce_kernel(
    const float* __restrict__ partial, int n, float* __restrict__ out,
    double inv_count)
{
    __shared__ double ws[4];
    const float4* p4 = (const float4*)partial;
    const int n4 = n >> 2;
    double s = 0.0;
    for (int i = threadIdx.x; i < n4; i += 256) {
        float4 v = p4[i];
        s += (double)v.x + (double)v.y + (double)v.z + (double)v.w;
    }
#pragma unroll
    for (int off = 32; off > 0; off >>= 1) s += __shfl_down(s, off, 64);
    int lane = threadIdx.x & 63, wid = threadIdx.x >> 6;
    if (lane == 0) ws[wid] = s;
    __syncthreads();
    if (threadIdx.x == 0) {
        double tot = ws[0] + ws[1] + ws[2] + ws[3];
        out[0] = (float)(1.0 - tot * inv_count);
    }
}

extern "C" void kernel_launch(void* const* d_in, const int* in_sizes, int n_in,
                              void* d_out, int out_size, void* d_ws, size_t ws_size,
                              hipStream_t stream) {
    const float* x = (const float*)d_in[0];
    const float* y = (const float*)d_in[1];
    float* partial = (float*)d_ws;

    const int N = 32;
    dim3 grid(64, N);   // 16 strips x 4 segments; grid.y = batch (C packed)
    ssim_roll_kernel<<<grid, THREADS, 0, stream>>>(x, y, partial);

    const int nPartial = 64 * N;                       // 2048
    const double inv_count = 1.0 / ((double)N * 2 * 512 * 512);
    ssim_reduce_kernel<<<1, 256, 0, stream>>>(partial, nPartial, (float*)d_out,
                                              inv_count);
}

// Round 25
// 65.572 us; speedup vs baseline: 1.0183x; 1.0065x over previous
//
#include <hip/hip_runtime.h>
#include <hip/hip_fp16.h>

// FINAL: R19 configuration — measured best (63.7us) across 24 rounds.
// Rolling-strip SSIM, 128-row segments, 48-row ring + 13 ghost rows,
// 2 barriers/chunk, 2048 blocks. Later variants (rot, 1-barrier, 74-ring,
// 512-thr, reg-prefetch) all measured neutral-to-worse; reverting to best.

#define KSZ 11
#define RMOD 48       /* ring rows; slot = q % 48 */
#define GH 13         /* ghost rows: V reads slots sb..sb+13, sb <= 47 */
#define ROWB 512      /* bytes per LDS row (union: lin 48x8=384, hbuf 32x16) */
#define THREADS 256
#define NCHUNK 4      /* 4 chunks x 32 rows = 128-row segment */

// Normalized 1-D Gaussian, sigma=1.5, K=11.
#define W0 1.0283800e-03f
#define W1 7.5987000e-03f
#define W2 3.6000800e-02f
#define W3 1.0936070e-01f
#define W4 2.1300550e-01f
#define W5 2.6601170e-01f

struct Pix8   { __half2 hx, hy; };                 // staged input px (2ch x,y)
struct Pix8x2 { __half2 hx0, hy0, hx1, hy1; };     // two adjacent Pix8 (16B)
struct Pix16  { __half2 s0, s1, s2, s3; };         // H-blurred 4 signals (16B)

// hbuf column swizzle (R16-proven): logical col 4g+j -> ((g+2j)&7)|(j<<3).
#define HBCOL(g, j) ((((g) + 2 * (j)) & 7) | ((j) << 3))

static __device__ __forceinline__ __half2 pkrtz(float a, float b) {
    auto v = __builtin_amdgcn_cvt_pkrtz(a, b);
    __half2 r;
    __builtin_memcpy(&r, &v, 4);
    return r;
}

// Stage global row q (48-col strip, base tileC-8) into lin ring slot s.
static __device__ __forceinline__ void stage_item(
    const float* __restrict__ x, const float* __restrict__ y,
    size_t base0, size_t base1, int q, int g, int s, int tileC,
    bool fast, Pix8* lin)
{
    const int c0 = 6 * g;
    Pix8 p[6];
    if (fast) {  // col-interior strip AND q < 512 (q >= 0 guaranteed here)
        const size_t goff = (size_t)q * 512 + (size_t)(tileC - 8 + c0);
        const float2* X0 = (const float2*)(x + base0 + goff);
        const float2* X1 = (const float2*)(x + base1 + goff);
        const float2* Y0 = (const float2*)(y + base0 + goff);
        const float2* Y1 = (const float2*)(y + base1 + goff);
#pragma unroll
        for (int m = 0; m < 3; ++m) {
            float2 a0 = X0[m], a1 = X1[m], b0 = Y0[m], b1 = Y1[m];
            p[2*m].hx   = pkrtz(a0.x, a1.x);
            p[2*m].hy   = pkrtz(b0.x, b1.x);
            p[2*m+1].hx = pkrtz(a0.y, a1.y);
            p[2*m+1].hy = pkrtz(b0.y, b1.y);
        }
    } else {
#pragma unroll
        for (int m = 0; m < 6; ++m) {
            const int gc = tileC - 8 + c0 + m;
            float x0 = 0.f, x1 = 0.f, y0 = 0.f, y1 = 0.f;
            if (q >= 0 && q < 512 && gc >= 0 && gc < 512) {
                const size_t gg = (size_t)q * 512 + (size_t)gc;
                x0 = x[base0 + gg]; x1 = x[base1 + gg];
                y0 = y[base0 + gg]; y1 = y[base1 + gg];
            }
            p[m].hx = pkrtz(x0, x1);
            p[m].hy = pkrtz(y0, y1);
        }
    }
    Pix8x2* dst = (Pix8x2*)&lin[s * 64 + c0];   // byte s*512 + 8*c0
#pragma unroll
    for (int m = 0; m < 3; ++m) {
        Pix8x2 o;
        o.hx0 = p[2*m].hx;   o.hy0 = p[2*m].hy;
        o.hx1 = p[2*m+1].hx; o.hy1 = p[2*m+1].hy;
        dst[m] = o;
    }
}

// H-blur ring slot s (reads lin row s, writes hbuf row s + ghost dup).
static __device__ __forceinline__ void h_item(
    int g, int s, Pix8* lin, Pix16* hb, const __half2* w2, __half2 hz)
{
    const int c0 = g << 2;
    __half2 wx[16], wy[16];
    const Pix8x2* src = (const Pix8x2*)&lin[s * 64 + (c0 + 2)];
#pragma unroll
    for (int k = 0; k < 8; ++k) {
        Pix8x2 u = src[k];
        wx[2*k]   = u.hx0; wy[2*k]   = u.hy0;
        wx[2*k+1] = u.hx1; wy[2*k+1] = u.hy1;
    }
    __half2 pp[16], qq[16];
#pragma unroll
    for (int k = 1; k < 15; ++k) {
        pp[k] = __hfma2(wy[k], wy[k], __hmul2(wx[k], wx[k]));  // x^2+y^2
        qq[k] = __hmul2(wx[k], wy[k]);                          // x*y
    }
    __half2 s0[4] = {hz, hz, hz, hz}, s1[4] = {hz, hz, hz, hz};
    __half2 s2[4] = {hz, hz, hz, hz}, s3[4] = {hz, hz, hz, hz};
#pragma unroll
    for (int k = 1; k < 15; ++k) {
#pragma unroll
        for (int j = 0; j < 4; ++j) {
            const int tt = k - 1 - j;
            if (tt >= 0 && tt < KSZ) {
                s0[j] = __hfma2(w2[tt], wx[k], s0[j]);
                s1[j] = __hfma2(w2[tt], wy[k], s1[j]);
                s2[j] = __hfma2(w2[tt], pp[k], s2[j]);
                s3[j] = __hfma2(w2[tt], qq[k], s3[j]);
            }
        }
    }
    Pix16* orow = &hb[s * 32];
#pragma unroll
    for (int j = 0; j < 4; ++j) {
        Pix16 v;
        v.s0 = s0[j]; v.s1 = s1[j]; v.s2 = s2[j]; v.s3 = s3[j];
        orow[HBCOL(g, j)] = v;
    }
    if (s < GH) {                       // ghost dup so V reads never wrap
        Pix16* orow2 = orow + RMOD * 32;
#pragma unroll
        for (int j = 0; j < 4; ++j) {
            Pix16 v;
            v.s0 = s0[j]; v.s1 = s1[j]; v.s2 = s2[j]; v.s3 = s3[j];
            orow2[HBCOL(g, j)] = v;
        }
    }
}

// Rolling-strip SSIM, 128-row segments: ring 48(+13 ghost) x 512B = 31.2KB
// -> 5 blocks/CU; grid 2048 = 8 blocks/CU queued -> dynamic balance.
// Per chunk: [barrier] stage+H (octet-local, no internal barrier)
// [barrier] V + packed-f16 SSIM.
__global__ __launch_bounds__(THREADS) void ssim_roll_kernel(
    const float* __restrict__ x, const float* __restrict__ y,
    float* __restrict__ partial)
{
    __shared__ __align__(16) unsigned char smem[(RMOD + GH) * ROWB]; // 31232 B
    __shared__ float wsum[THREADS / 64];
    Pix8*  lin = (Pix8*)smem;
    Pix16* hb  = (Pix16*)smem;

    const __half2 w2[KSZ] = {
        __float2half2_rn(W0), __float2half2_rn(W1), __float2half2_rn(W2),
        __float2half2_rn(W3), __float2half2_rn(W4), __float2half2_rn(W5),
        __float2half2_rn(W4), __float2half2_rn(W3), __float2half2_rn(W2),
        __float2half2_rn(W1), __float2half2_rn(W0)};
    const __half2 hz = __float2half2_rn(0.0f);

    const int tid = threadIdx.x;
    const int bx = blockIdx.x;                     // 0..63
    // XCD swizzle: XCD k (= bx&7) owns strips 2k,2k+1 (all 4 segments)
    const int t  = ((bx & 7) << 3) | (bx >> 3);    // bijective 0..63
    const int sx = t >> 2;                         // column strip 0..15
    const int sg = t & 3;                          // row segment 0..3
    const int B  = sg << 7;                        // first output row
    const int tileC = sx << 5;
    const bool colInt = (sx > 0) && (sx < 15);
    const size_t plane = 512 * 512;
    const size_t base0 = (size_t)blockIdx.y * 2 * plane;   // channel 0
    const size_t base1 = base0 + plane;                    // channel 1

    // ---- Prologue: hbuf rows B-5..B+4 (10 rows, 80 items) ----
    {
        const int pro_q = B - 5 + (tid >> 3);
        const int pro_g = tid & 7;
        const int pro_s = (pro_q + 480) % RMOD;    // +480 keeps operand >= 0
        if (tid < 80) {
            if (pro_q >= 0) {
                stage_item(x, y, base0, base1, pro_q, pro_g, pro_s, tileC,
                           colInt, lin);
                h_item(pro_g, pro_s, lin, hb, w2, hz);
            } else {       // rows < 0: blur of zero padding = zeros
                Pix16 z; z.s0 = hz; z.s1 = hz; z.s2 = hz; z.s3 = hz;
                Pix16* orow = &hb[pro_s * 32];     // pro_s in [43,47]: no ghost
#pragma unroll
                for (int j = 0; j < 4; ++j) orow[HBCOL(pro_g, j)] = z;
            }
        }
    }

    // ---- 4 chunks of 32 rows ----
    float bsum = 0.f;
    const int st_ro = tid >> 3, st_g = tid & 7;
    const int v_c = tid & 31, v_rg = tid >> 5;
    const int pc = HBCOL(v_c >> 2, v_c & 3);
    const __half2 c1h  = __float2half2_rn(1.0e-4f);
    const __half2 c2h  = __float2half2_rn(9.0e-4f);
    const __half2 twoh = __float2half2_rn(2.0f);

#pragma unroll 1
    for (int n = 0; n < NCHUNK; ++n) {
        __syncthreads();   // V(n-1) ring reads done before slots reused
        const int q = B + (n << 5) + 5 + st_ro;    // input rows [B+32n+5, +36]
        const int s = q % RMOD;
        const bool fast = colInt && (q < 512);
        stage_item(x, y, base0, base1, q, st_g, s, tileC, fast, lin);
        h_item(st_g, s, lin, hb, w2, hz);          // octet-local: no barrier
        __syncthreads();   // all 42 hbuf rows of this window ready

        // V-pass: output rows B+32n+4*v_rg .. +3, col v_c
        const int sb = (B + (n << 5) + (v_rg << 2) - 5 + 480) % RMOD;
        const Pix16* colp = &hb[sb * 32 + pc];     // reads sb..sb+13 (ghosts)

        __half2 b0[4] = {hz, hz, hz, hz}, b1[4] = {hz, hz, hz, hz};
        __half2 b2[4] = {hz, hz, hz, hz}, b3[4] = {hz, hz, hz, hz};
#pragma unroll
        for (int k = 0; k < 14; ++k) {
            Pix16 u = colp[k * 32];                // byte offset k*512: static
#pragma unroll
            for (int j = 0; j < 4; ++j) {
                const int tt = k - j;
                if (tt >= 0 && tt < KSZ) {
                    b0[j] = __hfma2(w2[tt], u.s0, b0[j]);
                    b1[j] = __hfma2(w2[tt], u.s1, b1[j]);
                    b2[j] = __hfma2(w2[tt], u.s2, b2[j]);
                    b3[j] = __hfma2(w2[tt], u.s3, b3[j]);
                }
            }
        }
        __half2 acc2 = hz;
#pragma unroll
        for (int j = 0; j < 4; ++j) {
            __half2 ux = b0[j], uy = b1[j], up = b2[j], uq = b3[j];
            __half2 uxuy  = __hmul2(ux, uy);
            __half2 sumsq = __hfma2(ux, ux, __hmul2(uy, uy));
            __half2 vsum  = __hsub2(up, sumsq);            // vx + vy
            __half2 vxy   = __hsub2(uq, uxuy);
            __half2 num   = __hmul2(__hfma2(twoh, uxuy, c1h),
                                    __hfma2(twoh, vxy, c2h));
            __half2 den   = __hmul2(__hadd2(sumsq, c1h), __hadd2(vsum, c2h));
            acc2 = __hfma2(num, h2rcp(den), acc2);
        }
        float2 af = __half22float2(acc2);
        bsum += af.x + af.y;
    }

    // ---- Wave shuffle reduce, cross-wave via LDS ----
#pragma unroll
    for (int off = 32; off > 0; off >>= 1) bsum += __shfl_down(bsum, off, 64);
    const int lane = tid & 63, wid = tid >> 6;
    if (lane == 0) wsum[wid] = bsum;
    __syncthreads();
    if (tid == 0) {
        float tot = 0.f;
#pragma unroll
        for (int i = 0; i < THREADS / 64; ++i) tot += wsum[i];
        partial[(size_t)blockIdx.y * gridDim.x + blockIdx.x] = tot;
    }
}

// Final deterministic reduction: n partials (float4-vectorized) ->
// out[0] = 1 - sum/count.
__global__ __launch_bounds__(256) void ssim_reduce_kernel(
    const float* __restrict__ partial, int n, float* __restrict__ out,
    double inv_count)
{
    __shared__ double ws[4];
    const float4* p4 = (const float4*)partial;
    const int n4 = n >> 2;
    double s = 0.0;
    for (int i = threadIdx.x; i < n4; i += 256) {
        float4 v = p4[i];
        s += (double)v.x + (double)v.y + (double)v.z + (double)v.w;
    }
#pragma unroll
    for (int off = 32; off > 0; off >>= 1) s += __shfl_down(s, off, 64);
    int lane = threadIdx.x & 63, wid = threadIdx.x >> 6;
    if (lane == 0) ws[wid] = s;
    __syncthreads();
    if (threadIdx.x == 0) {
        double tot = ws[0] + ws[1] + ws[2] + ws[3];
        out[0] = (float)(1.0 - tot * inv_count);
    }
}

extern "C" void kernel_launch(void* const* d_in, const int* in_sizes, int n_in,
                              void* d_out, int out_size, void* d_ws, size_t ws_size,
                              hipStream_t stream) {
    const float* x = (const float*)d_in[0];
    const float* y = (const float*)d_in[1];
    float* partial = (float*)d_ws;

    const int N = 32;
    dim3 grid(64, N);   // 16 strips x 4 segments; grid.y = batch (C packed)
    ssim_roll_kernel<<<grid, THREADS, 0, stream>>>(x, y, partial);

    const int nPartial = 64 * N;                       // 2048
    const double inv_count = 1.0 / ((double)N * 2 * 512 * 512);
    ssim_reduce_kernel<<<1, 256, 0, stream>>>(partial, nPartial, (float*)d_out,
                                              inv_count);
}

// Round 26
// 57.905 us; speedup vs baseline: 1.1531x; 1.1324x over previous
//
#include <hip/hip_runtime.h>
#include <hip/hip_fp16.h>

// R19 structure (measured best across 25 rounds) + uniform-stage fix:
// per-item validity classing makes the scalar masked path cover only the
// single mixed 6-col group on edge strips (was: all groups), and OOB rows
// become a 3-store zero shortcut. Removes the laggard concentration on
// XCD 0/7 (edge strips) and sg=3 (rows >= 512).

#define KSZ 11
#define RMOD 48       /* ring rows; slot = q % 48 */
#define GH 13         /* ghost rows: V reads slots sb..sb+13, sb <= 47 */
#define ROWB 512      /* bytes per LDS row (union: lin 48x8=384, hbuf 32x16) */
#define THREADS 256
#define NCHUNK 4      /* 4 chunks x 32 rows = 128-row segment */

// Normalized 1-D Gaussian, sigma=1.5, K=11.
#define W0 1.0283800e-03f
#define W1 7.5987000e-03f
#define W2 3.6000800e-02f
#define W3 1.0936070e-01f
#define W4 2.1300550e-01f
#define W5 2.6601170e-01f

struct Pix8   { __half2 hx, hy; };                 // staged input px (2ch x,y)
struct Pix8x2 { __half2 hx0, hy0, hx1, hy1; };     // two adjacent Pix8 (16B)
struct Pix16  { __half2 s0, s1, s2, s3; };         // H-blurred 4 signals (16B)

// hbuf column swizzle (R16-proven): logical col 4g+j -> ((g+2j)&7)|(j<<3).
#define HBCOL(g, j) ((((g) + 2 * (j)) & 7) | ((j) << 3))

static __device__ __forceinline__ __half2 pkrtz(float a, float b) {
    auto v = __builtin_amdgcn_cvt_pkrtz(a, b);
    __half2 r;
    __builtin_memcpy(&r, &v, 4);
    return r;
}

// Stage global row q (>=0) cols [tileC-8+6g, +5] into lin ring slot s.
// Validity classes: fast (vector), all-OOB (zero shortcut), mixed (scalar).
static __device__ __forceinline__ void stage_item(
    const float* __restrict__ x, const float* __restrict__ y,
    size_t base0, size_t base1, int q, int g, int s, int tileC, Pix8* lin)
{
    const int c0 = 6 * g;
    const int colLo = tileC - 8 + c0;
    Pix8x2* dst = (Pix8x2*)&lin[s * 64 + c0];   // byte s*512 + 8*c0

    const bool rowOK = (q < 512);
    const bool allCol = (colLo >= 0) && (colLo + 5 < 512);
    if (rowOK && allCol) {                       // fast vector path
        const size_t goff = (size_t)q * 512 + (size_t)colLo;
        const float2* X0 = (const float2*)(x + base0 + goff);
        const float2* X1 = (const float2*)(x + base1 + goff);
        const float2* Y0 = (const float2*)(y + base0 + goff);
        const float2* Y1 = (const float2*)(y + base1 + goff);
#pragma unroll
        for (int m = 0; m < 3; ++m) {
            float2 a0 = X0[m], a1 = X1[m], b0 = Y0[m], b1 = Y1[m];
            Pix8x2 o;
            o.hx0 = pkrtz(a0.x, a1.x);
            o.hy0 = pkrtz(b0.x, b1.x);
            o.hx1 = pkrtz(a0.y, a1.y);
            o.hy1 = pkrtz(b0.y, b1.y);
            dst[m] = o;
        }
    } else if (!rowOK || colLo + 5 < 0 || colLo >= 512) {  // all-OOB: zeros
        const __half2 hz = __float2half2_rn(0.0f);
        Pix8x2 z; z.hx0 = hz; z.hy0 = hz; z.hx1 = hz; z.hy1 = hz;
#pragma unroll
        for (int m = 0; m < 3; ++m) dst[m] = z;
    } else {                                     // mixed: masked scalar loads
        Pix8 p[6];
#pragma unroll
        for (int m = 0; m < 6; ++m) {
            const int gc = colLo + m;
            float x0 = 0.f, x1 = 0.f, y0 = 0.f, y1 = 0.f;
            if (gc >= 0 && gc < 512) {
                const size_t gg = (size_t)q * 512 + (size_t)gc;
                x0 = x[base0 + gg]; x1 = x[base1 + gg];
                y0 = y[base0 + gg]; y1 = y[base1 + gg];
            }
            p[m].hx = pkrtz(x0, x1);
            p[m].hy = pkrtz(y0, y1);
        }
#pragma unroll
        for (int m = 0; m < 3; ++m) {
            Pix8x2 o;
            o.hx0 = p[2*m].hx;   o.hy0 = p[2*m].hy;
            o.hx1 = p[2*m+1].hx; o.hy1 = p[2*m+1].hy;
            dst[m] = o;
        }
    }
}

// H-blur ring slot s (reads lin row s, writes hbuf row s + ghost dup).
static __device__ __forceinline__ void h_item(
    int g, int s, Pix8* lin, Pix16* hb, const __half2* w2, __half2 hz)
{
    const int c0 = g << 2;
    __half2 wx[16], wy[16];
    const Pix8x2* src = (const Pix8x2*)&lin[s * 64 + (c0 + 2)];
#pragma unroll
    for (int k = 0; k < 8; ++k) {
        Pix8x2 u = src[k];
        wx[2*k]   = u.hx0; wy[2*k]   = u.hy0;
        wx[2*k+1] = u.hx1; wy[2*k+1] = u.hy1;
    }
    __half2 pp[16], qq[16];
#pragma unroll
    for (int k = 1; k < 15; ++k) {
        pp[k] = __hfma2(wy[k], wy[k], __hmul2(wx[k], wx[k]));  // x^2+y^2
        qq[k] = __hmul2(wx[k], wy[k]);                          // x*y
    }
    __half2 s0[4] = {hz, hz, hz, hz}, s1[4] = {hz, hz, hz, hz};
    __half2 s2[4] = {hz, hz, hz, hz}, s3[4] = {hz, hz, hz, hz};
#pragma unroll
    for (int k = 1; k < 15; ++k) {
#pragma unroll
        for (int j = 0; j < 4; ++j) {
            const int tt = k - 1 - j;
            if (tt >= 0 && tt < KSZ) {
                s0[j] = __hfma2(w2[tt], wx[k], s0[j]);
                s1[j] = __hfma2(w2[tt], wy[k], s1[j]);
                s2[j] = __hfma2(w2[tt], pp[k], s2[j]);
                s3[j] = __hfma2(w2[tt], qq[k], s3[j]);
            }
        }
    }
    Pix16* orow = &hb[s * 32];
#pragma unroll
    for (int j = 0; j < 4; ++j) {
        Pix16 v;
        v.s0 = s0[j]; v.s1 = s1[j]; v.s2 = s2[j]; v.s3 = s3[j];
        orow[HBCOL(g, j)] = v;
    }
    if (s < GH) {                       // ghost dup so V reads never wrap
        Pix16* orow2 = orow + RMOD * 32;
#pragma unroll
        for (int j = 0; j < 4; ++j) {
            Pix16 v;
            v.s0 = s0[j]; v.s1 = s1[j]; v.s2 = s2[j]; v.s3 = s3[j];
            orow2[HBCOL(g, j)] = v;
        }
    }
}

// Rolling-strip SSIM, 128-row segments: ring 48(+13 ghost) x 512B = 31.2KB
// -> 5 blocks/CU; grid 2048 = 8 blocks/CU queued. Per chunk:
// [barrier] stage+H (octet-local, no internal barrier) [barrier] V + SSIM.
__global__ __launch_bounds__(THREADS) void ssim_roll_kernel(
    const float* __restrict__ x, const float* __restrict__ y,
    float* __restrict__ partial)
{
    __shared__ __align__(16) unsigned char smem[(RMOD + GH) * ROWB]; // 31232 B
    __shared__ float wsum[THREADS / 64];
    Pix8*  lin = (Pix8*)smem;
    Pix16* hb  = (Pix16*)smem;

    const __half2 w2[KSZ] = {
        __float2half2_rn(W0), __float2half2_rn(W1), __float2half2_rn(W2),
        __float2half2_rn(W3), __float2half2_rn(W4), __float2half2_rn(W5),
        __float2half2_rn(W4), __float2half2_rn(W3), __float2half2_rn(W2),
        __float2half2_rn(W1), __float2half2_rn(W0)};
    const __half2 hz = __float2half2_rn(0.0f);

    const int tid = threadIdx.x;
    const int bx = blockIdx.x;                     // 0..63
    // XCD swizzle: XCD k (= bx&7) owns strips 2k,2k+1 (all 4 segments)
    const int t  = ((bx & 7) << 3) | (bx >> 3);    // bijective 0..63
    const int sx = t >> 2;                         // column strip 0..15
    const int sg = t & 3;                          // row segment 0..3
    const int B  = sg << 7;                        // first output row
    const int tileC = sx << 5;
    const size_t plane = 512 * 512;
    const size_t base0 = (size_t)blockIdx.y * 2 * plane;   // channel 0
    const size_t base1 = base0 + plane;                    // channel 1

    // ---- Prologue: hbuf rows B-5..B+4 (10 rows, 80 items) ----
    {
        const int pro_q = B - 5 + (tid >> 3);
        const int pro_g = tid & 7;
        const int pro_s = (pro_q + 480) % RMOD;    // +480 keeps operand >= 0
        if (tid < 80) {
            if (pro_q >= 0) {
                stage_item(x, y, base0, base1, pro_q, pro_g, pro_s, tileC, lin);
                h_item(pro_g, pro_s, lin, hb, w2, hz);
            } else {       // rows < 0: blur of zero padding = zeros
                Pix16 z; z.s0 = hz; z.s1 = hz; z.s2 = hz; z.s3 = hz;
                Pix16* orow = &hb[pro_s * 32];     // pro_s in [43,47]: no ghost
#pragma unroll
                for (int j = 0; j < 4; ++j) orow[HBCOL(pro_g, j)] = z;
            }
        }
    }

    // ---- 4 chunks of 32 rows ----
    float bsum = 0.f;
    const int st_ro = tid >> 3, st_g = tid & 7;
    const int v_c = tid & 31, v_rg = tid >> 5;
    const int pc = HBCOL(v_c >> 2, v_c & 3);
    const __half2 c1h  = __float2half2_rn(1.0e-4f);
    const __half2 c2h  = __float2half2_rn(9.0e-4f);
    const __half2 twoh = __float2half2_rn(2.0f);

#pragma unroll 1
    for (int n = 0; n < NCHUNK; ++n) {
        __syncthreads();   // V(n-1) ring reads done before slots reused
        const int q = B + (n << 5) + 5 + st_ro;    // input rows [B+32n+5, +36]
        const int s = q % RMOD;
        stage_item(x, y, base0, base1, q, st_g, s, tileC, lin);
        h_item(st_g, s, lin, hb, w2, hz);          // octet-local: no barrier
        __syncthreads();   // all 42 hbuf rows of this window ready

        // V-pass: output rows B+32n+4*v_rg .. +3, col v_c
        const int sb = (B + (n << 5) + (v_rg << 2) - 5 + 480) % RMOD;
        const Pix16* colp = &hb[sb * 32 + pc];     // reads sb..sb+13 (ghosts)

        __half2 b0[4] = {hz, hz, hz, hz}, b1[4] = {hz, hz, hz, hz};
        __half2 b2[4] = {hz, hz, hz, hz}, b3[4] = {hz, hz, hz, hz};
#pragma unroll
        for (int k = 0; k < 14; ++k) {
            Pix16 u = colp[k * 32];                // byte offset k*512: static
#pragma unroll
            for (int j = 0; j < 4; ++j) {
                const int tt = k - j;
                if (tt >= 0 && tt < KSZ) {
                    b0[j] = __hfma2(w2[tt], u.s0, b0[j]);
                    b1[j] = __hfma2(w2[tt], u.s1, b1[j]);
                    b2[j] = __hfma2(w2[tt], u.s2, b2[j]);
                    b3[j] = __hfma2(w2[tt], u.s3, b3[j]);
                }
            }
        }
        __half2 acc2 = hz;
#pragma unroll
        for (int j = 0; j < 4; ++j) {
            __half2 ux = b0[j], uy = b1[j], up = b2[j], uq = b3[j];
            __half2 uxuy  = __hmul2(ux, uy);
            __half2 sumsq = __hfma2(ux, ux, __hmul2(uy, uy));
            __half2 vsum  = __hsub2(up, sumsq);            // vx + vy
            __half2 vxy   = __hsub2(uq, uxuy);
            __half2 num   = __hmul2(__hfma2(twoh, uxuy, c1h),
                                    __hfma2(twoh, vxy, c2h));
            __half2 den   = __hmul2(__hadd2(sumsq, c1h), __hadd2(vsum, c2h));
            acc2 = __hfma2(num, h2rcp(den), acc2);
        }
        float2 af = __half22float2(acc2);
        bsum += af.x + af.y;
    }

    // ---- Wave shuffle reduce, cross-wave via LDS ----
#pragma unroll
    for (int off = 32; off > 0; off >>= 1) bsum += __shfl_down(bsum, off, 64);
    const int lane = tid & 63, wid = tid >> 6;
    if (lane == 0) wsum[wid] = bsum;
    __syncthreads();
    if (tid == 0) {
        float tot = 0.f;
#pragma unroll
        for (int i = 0; i < THREADS / 64; ++i) tot += wsum[i];
        partial[(size_t)blockIdx.y * gridDim.x + blockIdx.x] = tot;
    }
}

// Final deterministic reduction: n partials (float4-vectorized) ->
// out[0] = 1 - sum/count.
__global__ __launch_bounds__(256) void ssim_reduce_kernel(
    const float* __restrict__ partial, int n, float* __restrict__ out,
    double inv_count)
{
    __shared__ double ws[4];
    const float4* p4 = (const float4*)partial;
    const int n4 = n >> 2;
    double s = 0.0;
    for (int i = threadIdx.x; i < n4; i += 256) {
        float4 v = p4[i];
        s += (double)v.x + (double)v.y + (double)v.z + (double)v.w;
    }
#pragma unroll
    for (int off = 32; off > 0; off >>= 1) s += __shfl_down(s, off, 64);
    int lane = threadIdx.x & 63, wid = threadIdx.x >> 6;
    if (lane == 0) ws[wid] = s;
    __syncthreads();
    if (threadIdx.x == 0) {
        double tot = ws[0] + ws[1] + ws[2] + ws[3];
        out[0] = (float)(1.0 - tot * inv_count);
    }
}

extern "C" void kernel_launch(void* const* d_in, const int* in_sizes, int n_in,
                              void* d_out, int out_size, void* d_ws, size_t ws_size,
                              hipStream_t stream) {
    const float* x = (const float*)d_in[0];
    const float* y = (const float*)d_in[1];
    float* partial = (float*)d_ws;

    const int N = 32;
    dim3 grid(64, N);   // 16 strips x 4 segments; grid.y = batch (C packed)
    ssim_roll_kernel<<<grid, THREADS, 0, stream>>>(x, y, partial);

    const int nPartial = 64 * N;                       // 2048
    const double inv_count = 1.0 / ((double)N * 2 * 512 * 512);
    ssim_reduce_kernel<<<1, 256, 0, stream>>>(partial, nPartial, (float*)d_out,
                                              inv_count);
}